// Round 8
// baseline (278.317 us; speedup 1.0000x reference)
//
#include <hip/hip_runtime.h>
#include <stdint.h>

typedef __attribute__((ext_vector_type(8))) short bf16x8;
typedef __attribute__((ext_vector_type(4))) float f32x4;

#if __has_builtin(__builtin_amdgcn_exp2f)
#define EXP2F(x) __builtin_amdgcn_exp2f(x)
#else
#define EXP2F(x) exp2f(x)
#endif

__device__ __forceinline__ short f2bf(float f) {
    union { float f; uint32_t u; } c; c.f = f;
    return (short)((c.u + 0x7fffu + ((c.u >> 16) & 1u)) >> 16);
}

// async global->LDS 16B/lane: dest = wave-uniform base + lane*16
typedef __attribute__((address_space(1))) void gvoid;
typedef __attribute__((address_space(3))) void lvoid;
__device__ __forceinline__ void async_cp16(const void* g, void* l) {
    __builtin_amdgcn_global_load_lds((gvoid*)g, (lvoid*)l, 16, 0, 0);
}

// ---- prep: Wt2g chunk-major [16 kchunks][192 cols][32 k] bf16 + bcat[192] f32
__global__ void prep_kernel(const float* __restrict__ Wk, const float* __restrict__ bk,
                            const float* __restrict__ Wq, const float* __restrict__ bq,
                            const float* __restrict__ Wv, const float* __restrict__ bv,
                            short* __restrict__ Wt2g, float* __restrict__ bcat) {
    const int col = blockIdx.x;  // 0..191 (0-63=K, 64-127=Q, 128-191=V)
    const float* W; const float* bb; int c0;
    if (col < 64)       { W = Wk; bb = bk; c0 = col; }
    else if (col < 128) { W = Wq; bb = bq; c0 = col - 64; }
    else                { W = Wv; bb = bv; c0 = col - 128; }
    for (int c = threadIdx.x; c < 512; c += blockDim.x)
        Wt2g[(c >> 5) * (192 * 32) + col * 32 + (c & 31)] = f2bf(W[(size_t)c * 64 + c0]);
    if (threadIdx.x == 0) bcat[col] = bb[c0];
}

// ---- fused split-batch kernel: 512 blocks x 512 threads (8 waves), 2 blocks/CU ----
// Block (b, jh=blockIdx.x&1): jh=0 -> q-tiles 0..7 (K/V rows 0..127);
//                             jh=1 -> q-tiles 8..15 (K/V all 256 rows, redundant lower half).
// Wave w: GEMM m-tiles {w} (+{w+8} if jh=1); q-tile t_q = jh*8 + w.
// W (B-frags) read direct from global (L1/L2-hot). Q kept per-wave (Ps C->A roundtrip).
// LDS 75776 B: phase1 x dbuf @0 (2x32K, granule-swizzled);
//              phase2 Ks @0 (32K) | Vts @32768 (32K) | Ps @65536 (10240) — alias-safe
//              (Ks/Vts written only after the loop-end barrier).
#define PSTR 40

__global__ __launch_bounds__(512, 4) void fused_kernel(
    const float* __restrict__ x, const short* __restrict__ Wt2g,
    const float* __restrict__ bcat, float* __restrict__ out) {
    extern __shared__ __align__(16) char smem[];

    const int tid = threadIdx.x;
    const int wave = tid >> 6, lane = tid & 63;
    const int quad = lane >> 4, l16 = lane & 15;
    const int b = blockIdx.x >> 1;
    const int jh = blockIdx.x & 1;
    const int tq = jh * 8 + wave;            // this wave's q-tile

    // ================= phase 1: QKV projection =================
    f32x4 acc_kv[2][8];                      // [m-tile][K:0-3 | V:4-7]
    f32x4 acc_q[4];
#pragma unroll
    for (int m = 0; m < 2; m++)
#pragma unroll
        for (int i = 0; i < 8; i++) acc_kv[m][i] = (f32x4){0.f, 0.f, 0.f, 0.f};
#pragma unroll
    for (int i = 0; i < 4; i++) acc_q[i] = (f32x4){0.f, 0.f, 0.f, 0.f};

    const int xr = lane >> 3;        // row-within-granule (8 rows x 128B = 1KB)
    const int xsl = lane & 7;        // dest 16B slot
    const int glim = 2 * (jh + 1);   // jh=0: 16 granules (rows 0..127); jh=1: 32

    // granule i = rows 8i..8i+7; dest slot s' holds src slot s'^((row&3)<<1)
#define STAGE_X(kc, bufp)                                                           \
    for (int g = 0; g < 4; g++) if (g < glim) {                                     \
        const int i = wave + g * 8;                                                 \
        const int r = i * 8 + xr;                                                   \
        const int s = xsl ^ ((r & 3) << 1);                                         \
        async_cp16(x + ((size_t)b * 256 + r) * 512 + (kc) * 32 + s * 4,             \
                   smem + (bufp) * 32768 + i * 1024);                               \
    }

    STAGE_X(0, 0)
    __syncthreads();

    for (int kc = 0; kc < 16; kc++) {
        const int buf = kc & 1;
        if (kc < 15) { STAGE_X(kc + 1, buf ^ 1) }
        // A-frags from swizzled x LDS (rows of m-tiles w and w+8)
        bf16x8 a[2];
        {
            const int arow = wave * 16 + l16;
            const float* xa = (const float*)(smem + buf * 32768) +
                              arow * 32 + ((quad ^ (arow & 3)) << 3);
            f32x4 u0 = *(const f32x4*)xa, u1 = *(const f32x4*)(xa + 4);
#pragma unroll
            for (int i = 0; i < 4; i++) { a[0][i] = f2bf(u0[i]); a[0][4 + i] = f2bf(u1[i]); }
        }
        if (jh) {
            const int arow = (wave + 8) * 16 + l16;
            const float* xa = (const float*)(smem + buf * 32768) +
                              arow * 32 + ((quad ^ (arow & 3)) << 3);
            f32x4 u0 = *(const f32x4*)xa, u1 = *(const f32x4*)(xa + 4);
#pragma unroll
            for (int i = 0; i < 4; i++) { a[1][i] = f2bf(u0[i]); a[1][4 + i] = f2bf(u1[i]); }
        }
        const short* wkc = Wt2g + (size_t)kc * 6144 + l16 * 32 + quad * 8;
#pragma unroll
        for (int nt = 0; nt < 12; nt++) {
            bf16x8 bfrag = *(const bf16x8*)(wkc + nt * 512);
            if (nt < 4) {            // K cols
                acc_kv[0][nt] = __builtin_amdgcn_mfma_f32_16x16x32_bf16(a[0], bfrag, acc_kv[0][nt], 0, 0, 0);
                if (jh) acc_kv[1][nt] = __builtin_amdgcn_mfma_f32_16x16x32_bf16(a[1], bfrag, acc_kv[1][nt], 0, 0, 0);
            } else if (nt < 8) {     // Q cols — only this wave's q-tile
                acc_q[nt - 4] = __builtin_amdgcn_mfma_f32_16x16x32_bf16(a[jh], bfrag, acc_q[nt - 4], 0, 0, 0);
            } else {                 // V cols
                acc_kv[0][nt - 4] = __builtin_amdgcn_mfma_f32_16x16x32_bf16(a[0], bfrag, acc_kv[0][nt - 4], 0, 0, 0);
                if (jh) acc_kv[1][nt - 4] = __builtin_amdgcn_mfma_f32_16x16x32_bf16(a[1], bfrag, acc_kv[1][nt - 4], 0, 0, 0);
            }
        }
        __syncthreads();   // also fences x-staging space before epilogue aliases it
    }

    // ---- epilogue: K/V C-frags -> swizzled phase-2 LDS (aliases x staging) ----
    short* Ks  = (short*)smem;               // [256 rows][64 h], slot^(row&7)
    short* Vts = (short*)(smem + 32768);     // [64 h][256 s],   slot^(h&7)
    short* Ps  = (short*)(smem + 65536);     // per-wave 16 x PSTR
    const int mlim = jh ? 2 : 1;
#pragma unroll
    for (int m = 0; m < 2; m++) if (m < mlim) {
        const int rowb = (wave + m * 8) * 16 + quad * 4;
#pragma unroll
        for (int nt8 = 0; nt8 < 8; nt8++) {
            const int h = (nt8 & 3) * 16 + l16;
            const float bias = bcat[(nt8 < 4 ? 0 : 128) + h];
#pragma unroll
            for (int r = 0; r < 4; r++) {
                const short v = f2bf(acc_kv[m][nt8][r] + bias);
                const int row = rowb + r;
                if (nt8 < 4)
                    Ks[row * 64 + (((h >> 3) ^ (row & 7)) << 3) + (h & 7)] = v;
                else
                    Vts[h * 256 + (((row >> 3) ^ (h & 7)) << 3) + (row & 7)] = v;
            }
        }
    }

    // ---- Q C->A roundtrip via per-wave Ps (no cross-wave sync needed) ----
    short* myP = Ps + wave * (16 * PSTR);
    bf16x8 qf0, qf1;
#pragma unroll
    for (int half = 0; half < 2; half++) {
#pragma unroll
        for (int nt2 = 0; nt2 < 2; nt2++) {
            const int qi = half * 2 + nt2;
            const float bias = bcat[64 + qi * 16 + l16];
#pragma unroll
            for (int r = 0; r < 4; r++)
                myP[(quad * 4 + r) * PSTR + nt2 * 16 + l16] = f2bf(acc_q[qi][r] + bias);
        }
        if (half == 0) qf0 = *(const bf16x8*)&myP[l16 * PSTR + quad * 8];
        else           qf1 = *(const bf16x8*)&myP[l16 * PSTR + quad * 8];
    }
    __syncthreads();

    // ================= phase 2: causal attention, all-LDS =================
    const float sc2 = 0.125f * 1.44269504088896340736f;  // 1/sqrt(64) * log2(e)
    const int sw = l16 & 7;

    f32x4 St[16];
#pragma unroll
    for (int i = 0; i < 16; i++) St[i] = (f32x4){0.f, 0.f, 0.f, 0.f};
#pragma unroll
    for (int nt = 0; nt < 16; nt++) if (nt <= tq) {
        const int krow = nt * 16 + l16;
        bf16x8 kf0 = *(const bf16x8*)&Ks[krow * 64 + ((quad ^ (krow & 7)) << 3)];
        bf16x8 kf1 = *(const bf16x8*)&Ks[krow * 64 + (((4 + quad) ^ (krow & 7)) << 3)];
        St[nt] = __builtin_amdgcn_mfma_f32_16x16x32_bf16(qf0, kf0, St[nt], 0, 0, 0);
        St[nt] = __builtin_amdgcn_mfma_f32_16x16x32_bf16(qf1, kf1, St[nt], 0, 0, 0);
    }

    // mask + base-2 softmax; C-layout rows = quad*4+r, col = l16
    const int rowq = tq * 16 + quad * 4;
    float mx[4], ls[4];
#pragma unroll
    for (int r = 0; r < 4; r++) mx[r] = -3.0e38f;
#pragma unroll
    for (int nt = 0; nt < 16; nt++) if (nt <= tq) {
        const int cs = nt * 16 + l16;
#pragma unroll
        for (int r = 0; r < 4; r++) {
            float s = (cs <= rowq + r) ? St[nt][r] * sc2 : -3.0e38f;
            St[nt][r] = s;
            mx[r] = fmaxf(mx[r], s);
        }
    }
#pragma unroll
    for (int d = 1; d < 16; d <<= 1)
#pragma unroll
        for (int r = 0; r < 4; r++)
            mx[r] = fmaxf(mx[r], __shfl_xor(mx[r], d, 64));
#pragma unroll
    for (int r = 0; r < 4; r++) ls[r] = 0.f;
#pragma unroll
    for (int nt = 0; nt < 16; nt++) if (nt <= tq) {
#pragma unroll
        for (int r = 0; r < 4; r++) {
            float p = EXP2F(St[nt][r] - mx[r]);
            St[nt][r] = p;                 // St[nt>tq] stays 0 == correct P
            ls[r] += p;
        }
    }
#pragma unroll
    for (int d = 1; d < 16; d <<= 1)
#pragma unroll
        for (int r = 0; r < 4; r++)
            ls[r] += __shfl_xor(ls[r], d, 64);

    // O = P V over 32-s chunks; P via wave-local LDS C->A roundtrip
    f32x4 O[4];
#pragma unroll
    for (int i = 0; i < 4; i++) O[i] = (f32x4){0.f, 0.f, 0.f, 0.f};
    const int nch = (tq + 2) >> 1;         // ceil((tq+1)/2), wave-uniform
#pragma unroll
    for (int c2 = 0; c2 < 8; c2++) if (c2 < nch) {
#pragma unroll
        for (int t2i = 0; t2i < 2; t2i++) {
            const int nt = c2 * 2 + t2i;   // St[nt]=0 beyond diagonal => P=0
#pragma unroll
            for (int r = 0; r < 4; r++)
                myP[(quad * 4 + r) * PSTR + t2i * 16 + l16] = f2bf(St[nt][r]);
        }
        bf16x8 pf = *(const bf16x8*)&myP[l16 * PSTR + quad * 8];
#pragma unroll
        for (int ht = 0; ht < 4; ht++) {
            const int h = ht * 16 + l16;
            bf16x8 vf = *(const bf16x8*)&Vts[h * 256 + (((c2 * 4 + quad) ^ (h & 7)) << 3)];
            O[ht] = __builtin_amdgcn_mfma_f32_16x16x32_bf16(pf, vf, O[ht], 0, 0, 0);
        }
    }

    float rls[4];
#pragma unroll
    for (int r = 0; r < 4; r++) rls[r] = 1.0f / ls[r];
#pragma unroll
    for (int ht = 0; ht < 4; ht++)
#pragma unroll
        for (int r = 0; r < 4; r++)
            out[((size_t)b * 256 + rowq + r) * 64 + ht * 16 + l16] = O[ht][r] * rls[r];
#undef STAGE_X
}

extern "C" void kernel_launch(void* const* d_in, const int* in_sizes, int n_in,
                              void* d_out, int out_size, void* d_ws, size_t ws_size,
                              hipStream_t stream) {
    const float* x  = (const float*)d_in[0];
    const float* Wk = (const float*)d_in[1];
    const float* bk = (const float*)d_in[2];
    const float* Wq = (const float*)d_in[3];
    const float* bq = (const float*)d_in[4];
    const float* Wv = (const float*)d_in[5];
    const float* bv = (const float*)d_in[6];
    float* out = (float*)d_out;

    char* ws = (char*)d_ws;
    short* Wt2g = (short*)(ws);             // 196608 B (chunk-major)
    float* bcat = (float*)(ws + 196608);    // 768 B

    const int smem_bytes = 75776;           // >64KB -> dynamic + attribute; 2 blocks/CU
    (void)hipFuncSetAttribute((const void*)fused_kernel,
                              hipFuncAttributeMaxDynamicSharedMemorySize, smem_bytes);

    prep_kernel<<<192, 256, 0, stream>>>(Wk, bk, Wq, bq, Wv, bv, Wt2g, bcat);
    fused_kernel<<<512, 512, smem_bytes, stream>>>(x, Wt2g, bcat, out);
}

// Round 9
// 221.751 us; speedup vs baseline: 1.2551x; 1.2551x over previous
//
#include <hip/hip_runtime.h>
#include <stdint.h>

typedef __attribute__((ext_vector_type(8))) short bf16x8;
typedef __attribute__((ext_vector_type(4))) float f32x4;
typedef __attribute__((ext_vector_type(16))) float f32x16;

#if __has_builtin(__builtin_amdgcn_exp2f)
#define EXP2F(x) __builtin_amdgcn_exp2f(x)
#else
#define EXP2F(x) exp2f(x)
#endif

// per-wave drain of own outstanding vmem (vmcnt(0), exp/lgkm unconstrained)
#define WAITV0() __builtin_amdgcn_s_waitcnt(0x0F70)

__device__ __forceinline__ short f2bf(float f) {
    union { float f; uint32_t u; } c; c.f = f;
    return (short)((c.u + 0x7fffu + ((c.u >> 16) & 1u)) >> 16);
}

// async global->LDS 16B/lane: dest = wave-uniform base + lane*16
typedef __attribute__((address_space(1))) void gvoid;
typedef __attribute__((address_space(3))) void lvoid;
__device__ __forceinline__ void async_cp16(const void* g, void* l) {
    __builtin_amdgcn_global_load_lds((gvoid*)g, (lvoid*)l, 16, 0, 0);
}

// ---- prep: Wt3 [32 ksteps][6 n32][32 col][2 kh][8 k] bf16 (dense 1KB B-frags) + bcat[192]
__global__ void prep_kernel(const float* __restrict__ Wk, const float* __restrict__ bk,
                            const float* __restrict__ Wq, const float* __restrict__ bq,
                            const float* __restrict__ Wv, const float* __restrict__ bv,
                            short* __restrict__ Wt3, float* __restrict__ bcat) {
    const int col = blockIdx.x;  // 0..191 (0-63=K, 64-127=Q, 128-191=V)
    const float* W; const float* bb; int c0;
    if (col < 64)       { W = Wk; bb = bk; c0 = col; }
    else if (col < 128) { W = Wq; bb = bq; c0 = col - 64; }
    else                { W = Wv; bb = bv; c0 = col - 128; }
    const int n32 = col >> 5, cc = col & 31;
    for (int c = threadIdx.x; c < 512; c += blockDim.x) {
        const int kstep = c >> 4, khh = (c >> 3) & 1, i = c & 7;
        Wt3[(size_t)(kstep * 6 + n32) * 512 + cc * 16 + khh * 8 + i] = f2bf(W[(size_t)c * 64 + c0]);
    }
    if (threadIdx.x == 0) bcat[col] = bb[c0];
}

// ---- fused per-batch kernel: barrier-free QKV GEMM -> LDS -> causal attention ----
// grid 256 (1 block/batch), 1024 thr = 16 waves. Wave w = (m32 = w>>1, ng = w&1):
// 3 output 32x32 tiles (n32 = {ng, 2+ng, 4+ng} = K/Q/V halves) over its 32 rows.
// Phase 1: per-wave private x staging (8KB dbuf, async DMA), W from global dense
// 1KB reg loads, 32x32x16 MFMA, NO barriers (per-wave vmcnt only).
// Phase 2: R7-verified all-LDS attention, q-tile = wave.
// LDS 131072 B: phase1 = wave*8192 private (2x4KB dbuf).
//   phase2 aliases: Ks@0 32K | Qs@32768 32K | Vts@65536 32K | Ps@98304 20K.
#define PSTR 40

__global__ __launch_bounds__(1024, 4) void fused_kernel(
    const float* __restrict__ x, const short* __restrict__ Wt3,
    const float* __restrict__ bcat, float* __restrict__ out) {
    extern __shared__ __align__(16) char smem[];

    const int tid = threadIdx.x;
    const int wave = tid >> 6, lane = tid & 63;
    const int quad = lane >> 4, l16 = lane & 15;
    const int l32 = lane & 31, kh = lane >> 5;
    const int b = blockIdx.x;
    const int m32 = wave >> 1, ng = wave & 1;

    // ================= phase 1: QKV projection (barrier-free) =================
    f32x16 acc[3];
#pragma unroll
    for (int t = 0; t < 3; t++)
#pragma unroll
        for (int i = 0; i < 16; i++) acc[t][i] = 0.f;

    char* sbase = smem + wave * 8192;        // wave-private staging
    const int srow = lane >> 3;              // row-within-granule (8 rows x 128B)
    const int ssl = (lane & 7) ^ srow;       // swizzled src slot -> LDS[row][s']=x[row][s'^(row&7)]

#define STAGE_X(kc, bufp)                                                            \
    for (int g = 0; g < 4; g++)                                                      \
        async_cp16(x + ((size_t)b * 256 + m32 * 32 + g * 8 + srow) * 512 +           \
                       (kc) * 32 + ssl * 4,                                          \
                   sbase + (bufp) * 4096 + g * 1024);

    STAGE_X(0, 0)

#pragma unroll
    for (int kc = 0; kc < 16; kc++) {
        const int buf = kc & 1;
        WAITV0();   // own stage(kc) arrived (per-wave; no block barrier)
        // W B-frags: 6 dense 1KB loads (L1/L2-hot, same addrs all waves)
        bf16x8 wf[2][3];
#pragma unroll
        for (int ks = 0; ks < 2; ks++)
#pragma unroll
            for (int t = 0; t < 3; t++) {
                const int n32 = t * 2 + ng;
                wf[ks][t] = *(const bf16x8*)&Wt3[(size_t)((kc * 2 + ks) * 6 + n32) * 512 +
                                                 l32 * 16 + kh * 8];
            }
        // A frags from own staging: row=l32, k = ks*16 + kh*8 + i
        bf16x8 a[2];
#pragma unroll
        for (int ks = 0; ks < 2; ks++) {
            const float* ap = (const float*)(sbase + buf * 4096 + l32 * 128);
            const int s0 = (ks * 4 + kh * 2 + 0) ^ (l32 & 7);
            const int s1 = (ks * 4 + kh * 2 + 1) ^ (l32 & 7);
            f32x4 u0 = *(const f32x4*)(ap + s0 * 4);
            f32x4 u1 = *(const f32x4*)(ap + s1 * 4);
#pragma unroll
            for (int i = 0; i < 4; i++) { a[ks][i] = f2bf(u0[i]); a[ks][4 + i] = f2bf(u1[i]); }
        }
        if (kc < 15) { STAGE_X(kc + 1, buf ^ 1) }
#pragma unroll
        for (int ks = 0; ks < 2; ks++)
#pragma unroll
            for (int t = 0; t < 3; t++)
                acc[t] = __builtin_amdgcn_mfma_f32_32x32x16_bf16(a[ks], wf[ks][t], acc[t], 0, 0, 0);
    }

    __syncthreads();   // barrier #1: all phase-1 LDS reads done

    // ---- epilogue: 32x32 C-layout (col=lane&31, row=(reg&3)+8*(reg>>2)+4*kh) ----
    short* Ks  = (short*)smem;               // [256 rows][64 h], slot^(row&7)
    short* Qs  = (short*)(smem + 32768);     // [256 rows][64 h], slot^(row&7)
    short* Vts = (short*)(smem + 65536);     // [64 h][256 s],   slot^(h&7)
    short* Ps  = (short*)(smem + 98304);     // per-wave 16 x PSTR
#pragma unroll
    for (int t = 0; t < 3; t++) {
        const int h = ng * 32 + l32;
        const float bias = bcat[t * 64 + h];
#pragma unroll
        for (int reg = 0; reg < 16; reg++) {
            const int row = m32 * 32 + (reg & 3) + 8 * (reg >> 2) + 4 * kh;
            const short v = f2bf(acc[t][reg] + bias);
            if (t == 0)      Ks[row * 64 + (((h >> 3) ^ (row & 7)) << 3) + (h & 7)] = v;
            else if (t == 1) Qs[row * 64 + (((h >> 3) ^ (row & 7)) << 3) + (h & 7)] = v;
            else             Vts[h * 256 + (((row >> 3) ^ (h & 7)) << 3) + (row & 7)] = v;
        }
    }
    __syncthreads();   // barrier #2: K/Q/V visible

    // ================= phase 2: causal attention, all-LDS (R7-verified) =================
    const float sc2 = 0.125f * 1.44269504088896340736f;  // 1/sqrt(64) * log2(e)
    short* myP = Ps + wave * (16 * PSTR);
    const int tq = wave;

    const int qrow = tq * 16 + l16;
    const int sw = l16 & 7;
    bf16x8 qf0 = *(const bf16x8*)&Qs[qrow * 64 + ((quad ^ sw) << 3)];
    bf16x8 qf1 = *(const bf16x8*)&Qs[qrow * 64 + (((4 + quad) ^ sw) << 3)];

    f32x4 St[16];
#pragma unroll
    for (int i = 0; i < 16; i++) St[i] = (f32x4){0.f, 0.f, 0.f, 0.f};
#pragma unroll
    for (int nt = 0; nt < 16; nt++) if (nt <= tq) {
        const int krow = nt * 16 + l16;
        bf16x8 kf0 = *(const bf16x8*)&Ks[krow * 64 + ((quad ^ (krow & 7)) << 3)];
        bf16x8 kf1 = *(const bf16x8*)&Ks[krow * 64 + (((4 + quad) ^ (krow & 7)) << 3)];
        St[nt] = __builtin_amdgcn_mfma_f32_16x16x32_bf16(qf0, kf0, St[nt], 0, 0, 0);
        St[nt] = __builtin_amdgcn_mfma_f32_16x16x32_bf16(qf1, kf1, St[nt], 0, 0, 0);
    }

    // mask + base-2 softmax; C-layout rows = quad*4+r, col = l16
    const int rowq = tq * 16 + quad * 4;
    float mx[4], ls[4];
#pragma unroll
    for (int r = 0; r < 4; r++) mx[r] = -3.0e38f;
#pragma unroll
    for (int nt = 0; nt < 16; nt++) if (nt <= tq) {
        const int cs = nt * 16 + l16;
#pragma unroll
        for (int r = 0; r < 4; r++) {
            float s = (cs <= rowq + r) ? St[nt][r] * sc2 : -3.0e38f;
            St[nt][r] = s;
            mx[r] = fmaxf(mx[r], s);
        }
    }
#pragma unroll
    for (int d = 1; d < 16; d <<= 1)
#pragma unroll
        for (int r = 0; r < 4; r++)
            mx[r] = fmaxf(mx[r], __shfl_xor(mx[r], d, 64));
#pragma unroll
    for (int r = 0; r < 4; r++) ls[r] = 0.f;
#pragma unroll
    for (int nt = 0; nt < 16; nt++) if (nt <= tq) {
#pragma unroll
        for (int r = 0; r < 4; r++) {
            float p = EXP2F(St[nt][r] - mx[r]);
            St[nt][r] = p;                 // St[nt>tq] stays 0 == correct P
            ls[r] += p;
        }
    }
#pragma unroll
    for (int d = 1; d < 16; d <<= 1)
#pragma unroll
        for (int r = 0; r < 4; r++)
            ls[r] += __shfl_xor(ls[r], d, 64);

    // O = P V over 32-s chunks; P via wave-local LDS C->A roundtrip
    f32x4 O[4];
#pragma unroll
    for (int i = 0; i < 4; i++) O[i] = (f32x4){0.f, 0.f, 0.f, 0.f};
    const int nch = (tq + 2) >> 1;         // ceil((tq+1)/2), wave-uniform
#pragma unroll
    for (int c2 = 0; c2 < 8; c2++) if (c2 < nch) {
#pragma unroll
        for (int t2i = 0; t2i < 2; t2i++) {
            const int nt = c2 * 2 + t2i;   // St[nt]=0 beyond diagonal => P=0
#pragma unroll
            for (int r = 0; r < 4; r++)
                myP[(quad * 4 + r) * PSTR + t2i * 16 + l16] = f2bf(St[nt][r]);
        }
        bf16x8 pf = *(const bf16x8*)&myP[l16 * PSTR + quad * 8];
#pragma unroll
        for (int ht = 0; ht < 4; ht++) {
            const int h = ht * 16 + l16;
            bf16x8 vf = *(const bf16x8*)&Vts[h * 256 + (((c2 * 4 + quad) ^ (h & 7)) << 3)];
            O[ht] = __builtin_amdgcn_mfma_f32_16x16x32_bf16(pf, vf, O[ht], 0, 0, 0);
        }
    }

    float rls[4];
#pragma unroll
    for (int r = 0; r < 4; r++) rls[r] = 1.0f / ls[r];
#pragma unroll
    for (int ht = 0; ht < 4; ht++)
#pragma unroll
        for (int r = 0; r < 4; r++)
            out[((size_t)b * 256 + rowq + r) * 64 + ht * 16 + l16] = O[ht][r] * rls[r];
#undef STAGE_X
}

extern "C" void kernel_launch(void* const* d_in, const int* in_sizes, int n_in,
                              void* d_out, int out_size, void* d_ws, size_t ws_size,
                              hipStream_t stream) {
    const float* x  = (const float*)d_in[0];
    const float* Wk = (const float*)d_in[1];
    const float* bk = (const float*)d_in[2];
    const float* Wq = (const float*)d_in[3];
    const float* bq = (const float*)d_in[4];
    const float* Wv = (const float*)d_in[5];
    const float* bv = (const float*)d_in[6];
    float* out = (float*)d_out;

    char* ws = (char*)d_ws;
    short* Wt3  = (short*)(ws);             // 196608 B (kstep-major dense-frag layout)
    float* bcat = (float*)(ws + 196608);    // 768 B

    const int smem_bytes = 131072;          // >64KB -> dynamic + attribute; 1 block/CU
    (void)hipFuncSetAttribute((const void*)fused_kernel,
                              hipFuncAttributeMaxDynamicSharedMemorySize, smem_bytes);

    prep_kernel<<<192, 256, 0, stream>>>(Wk, bk, Wq, bq, Wv, bv, Wt3, bcat);
    fused_kernel<<<256, 1024, smem_bytes, stream>>>(x, Wt3, bcat, out);
}